// Round 9
// baseline (9.837 us; speedup 1.0000x reference)
//
#include <hip/hip_runtime.h>

#define N 2048
#define BATCH 32
#define BLOCK 512
#define WAVES (BLOCK / 64)
#define NM 11           // moments M_1..M_11
#define KT 11           // series terms t^0..t^10

// Rank-1 attention via moment expansion:
//   y_i = W(t_i)/Z(t_i),  t_i = x_i/16
//   Z(t) = sum_k t^k/k! M_k,  W(t) = Z'(t) = sum_k t^k/k! M_{k+1}
// |t*x_j| <= ~1.45 worst-case -> 11-term remainder ~6e-6 rel (threshold 6e-3).
// R9: lean-latency variant of R8 (K 14->11, power tree depth 4 instead of a
// 14-deep serial chain) to discriminate in-kernel latency vs dispatch floor.
__global__ __launch_bounds__(BLOCK) void rank1_attn_kernel(
    const float* __restrict__ x, float* __restrict__ y) {
    __shared__ float smom[WAVES][NM];

    const int b    = blockIdx.x;
    const int tid  = threadIdx.x;
    const int lane = tid & 63;
    const int wv   = tid >> 6;

    // each thread owns one float4 of the row (512*4 = 2048)
    const float4 v = reinterpret_cast<const float4*>(x + b * N)[tid];
    const float xs[4] = {v.x, v.y, v.z, v.w};

    // ---- phase A: local moment partials M_1..M_11 (depth-4 power tree) ----
    float m[NM];
#pragma unroll
    for (int k = 0; k < NM; ++k) m[k] = 0.f;
#pragma unroll
    for (int e = 0; e < 4; ++e) {
        const float x1  = xs[e];
        const float x2  = x1 * x1;
        const float x3  = x2 * x1;
        const float x4  = x2 * x2;
        const float x5  = x4 * x1;
        const float x6  = x4 * x2;
        const float x7  = x4 * x3;
        const float x8  = x4 * x4;
        const float x9  = x8 * x1;
        const float x10 = x8 * x2;
        const float x11 = x8 * x3;
        m[0] += x1; m[1] += x2; m[2] += x3; m[3] += x4; m[4] += x5;
        m[5] += x6; m[6] += x7; m[7] += x8; m[8] += x9; m[9] += x10;
        m[10] += x11;
    }

    // 64-lane butterfly reduce (all lanes end with wave total)
#pragma unroll
    for (int off = 1; off < 64; off <<= 1) {
#pragma unroll
        for (int k = 0; k < NM; ++k) m[k] += __shfl_xor(m[k], off);
    }
    if (lane == 0) {
#pragma unroll
        for (int k = 0; k < NM; ++k) smom[wv][k] = m[k];
    }
    __syncthreads();

    // ---- cross-wave sum -> row moments (uniform, LDS broadcast reads) ----
    float c[NM + 1];
    c[0] = (float)N;                 // M_0
#pragma unroll
    for (int k = 0; k < NM; ++k) {
        float s = smom[0][k];
#pragma unroll
        for (int w = 1; w < WAVES; ++w) s += smom[w][k];
        c[k + 1] = s;
    }

    const float invf[KT] = {
        1.f, 1.f, 0.5f, 1.f / 6.f, 1.f / 24.f, 1.f / 120.f, 1.f / 720.f,
        1.f / 5040.f, 1.f / 40320.f, 1.f / 362880.f, 1.f / 3628800.f};
    float zc[KT], wc[KT];
#pragma unroll
    for (int k = 0; k < KT; ++k) {
        zc[k] = c[k] * invf[k];      // M_k / k!
        wc[k] = c[k + 1] * invf[k];  // M_{k+1} / k!
    }

    // ---- phase B: two Horner evals per output ----
    float4 out;
    float* op = reinterpret_cast<float*>(&out);
#pragma unroll
    for (int e = 0; e < 4; ++e) {
        const float t = xs[e] * (1.0f / 16.0f);
        float zz = zc[KT - 1];
        float ww = wc[KT - 1];
#pragma unroll
        for (int k = KT - 2; k >= 0; --k) {
            zz = zz * t + zc[k];
            ww = ww * t + wc[k];
        }
        op[e] = ww / zz;
    }
    reinterpret_cast<float4*>(y + b * N)[tid] = out;
}

extern "C" void kernel_launch(void* const* d_in, const int* in_sizes, int n_in,
                              void* d_out, int out_size, void* d_ws, size_t ws_size,
                              hipStream_t stream) {
    const float* x = (const float*)d_in[0];
    float* y = (float*)d_out;
    rank1_attn_kernel<<<dim3(BATCH), dim3(BLOCK), 0, stream>>>(x, y);
}